// Round 10
// baseline (3122.084 us; speedup 1.0000x reference)
//
#include <hip/hip_runtime.h>

#define TT 2048
#define HD 64

// LDS arena, 2 batch rows per block, h stored as FP16 (c stays f32 in regs):
//   h1 : [0, 640)       parity p at p*320, row r at r*160, unit j at j*2
//   h2 : [656, 1296)    same layout. H2_BASE ≡ 16 (mod 128): +4-bank skew.
//                       h1 reads hit bank-quads {0-3,8-11,16-19,24-27}, h2 reads
//                       {4-7,12-15,20-23,28-31} (parity +320B rotates within set)
//                       -> an L1 wave's 8 read addresses cover all 32 banks.
//   fcs: [1296, 1808)   f32 FC staging (2 rows x 64)
#define H1_BASE 0
#define H2_BASE 656
#define FCS_BASE 1296
#define PSTR 320
#define RSTR 160

// Gate pre-scales folded into (fp16) weights/biases at load time:
//   sigmoid gates (i,f,o): t = -log2(e)*z   -> sigma(z) = rcp(1+exp2(t))
//   tanh gate (g):         t = -2*log2(e)*z -> tanh(z)  = 2*rcp(1+exp2(t)) - 1
#define SIC -1.4426950408889634f
#define SGC -2.8853900817779268f

#if __has_builtin(__builtin_amdgcn_exp2f)
#define EXP2F(x) __builtin_amdgcn_exp2f(x)
#else
#define EXP2F(x) __expf(0.69314718055994531f * (x))
#endif
#if __has_builtin(__builtin_amdgcn_rcpf)
#define RCPF(x) __builtin_amdgcn_rcpf(x)
#else
#define RCPF(x) (1.0f / (x))
#endif

__device__ __forceinline__ float rcp1p(float t) { return RCPF(1.0f + EXP2F(t)); }

typedef _Float16 v2h __attribute__((ext_vector_type(2)));

// v_dot2_f32_f16: 2 fp16 products + f32 accumulate in ONE VALU instr.
#if __has_builtin(__builtin_amdgcn_fdot2)
#define FDOT2(a, b, c) __builtin_amdgcn_fdot2((a), (b), (c), false)
#else
#define FDOT2(a, b, c) __fmaf_rn((float)(a)[1], (float)(b)[1], __fmaf_rn((float)(a)[0], (float)(b)[0], (c)))
#endif

static __device__ __forceinline__ v2h bch(float f) { return __builtin_bit_cast(v2h, f); }
static __device__ __forceinline__ v2h packw(float a, float b, float s) {
    v2h r; r[0] = (_Float16)(a * s); r[1] = (_Float16)(b * s); return r;
}

// pure DPP cross-lane move (stays OFF the LDS pipe).
// Receiver lane i gets in[(i-n)&15] for row_ror:n.
// 0xB1 = quad_perm xor1, 0x4E = quad_perm xor2,
// 0x12C = row_ror:12 -> out[i] = in[(i+4)&15]  (the +4 fetch, verified R5).
template<int CTRL>
__device__ __forceinline__ float dpp_get(float v) {
    return __int_as_float(__builtin_amdgcn_update_dpp(0, __float_as_int(v), CTRL, 0xF, 0xF, true));
}

// Hot-loop barrier: order LDS ops only; let vmem/scalar prefetches ride across.
#define BARRIER() asm volatile("s_waitcnt lgkmcnt(0)\n\ts_barrier" ::: "memory")

// 16-K dot for one gate: 8 fdot2, first seeds from c=0 (inline const, no mov).
#define GDOT8I(acc, W) \
    acc = FDOT2(W##0, h0_, 0.0f); \
    acc = FDOT2(W##1, h1_, acc);  \
    acc = FDOT2(W##2, h2_, acc);  \
    acc = FDOT2(W##3, h3_, acc);  \
    acc = FDOT2(W##4, h4_, acc);  \
    acc = FDOT2(W##5, h5_, acc);  \
    acc = FDOT2(W##6, h6_, acc);  \
    acc = FDOT2(W##7, h7_, acc);

// One h-row (16 fp16 = 32B) in TWO ds_read_b128; 4 gates = 32 fdot2.
// P = pointer-set prefix (pe/po), parity baked in -> reg+imm addressing.
#define ROWDOTH(P, ROFF, A0, A1, A2, A3) { \
    const float4 f0_ = *(const float4*)(P##0 + (ROFF)); \
    const float4 f1_ = *(const float4*)(P##1 + (ROFF)); \
    const v2h h0_ = bch(f0_.x), h1_ = bch(f0_.y), h2_ = bch(f0_.z), h3_ = bch(f0_.w); \
    const v2h h4_ = bch(f1_.x), h5_ = bch(f1_.y), h6_ = bch(f1_.z), h7_ = bch(f1_.w); \
    GDOT8I(A0, wA) \
    GDOT8I(A1, wB) \
    GDOT8I(A2, wC) \
    GDOT8I(A3, wD) }

// 2-row packed quad reduction (structure verified in R3): lane rk ends with the
// full quad sum of row rk&1 (lanes rk and rk^2 duplicate). Stage1 pre-swaps rows
// so the xor1 partner delivers MY row's other-chunk partial; stage2 plain xor2.
#define QRED2(e, r0, r1) \
    float e; { \
        float x_ = rr1 ? (r1) : (r0); \
        float y_ = rr1 ? (r0) : (r1); \
        x_ += dpp_get<0xB1>(y_); \
        e = x_ + dpp_get<0x4E>(x_); \
    }

// One pipelined timestep. P = pointer set (pe even / po odd), X = x register
// (xa even / xb odd; each L0 lane streams only ITS row (rk&1)'s x stream),
// L0WOFF/L1WOFF = parity write byte offsets (0 / PSTR), DO_L1 gates L1,
// XNI = x prefetch index. Bias + x*Wih inject POST-QRED (once per lane).
#define STEP(P, X, L0WOFF, L1WOFF, DO_L1, XNI)                                  \
{                                                                               \
    float xv = 0.f;                                                             \
    if (isL0) {                                                                 \
        xv = X;                                                                 \
        const int xi_ = (XNI) < TT ? (XNI) : (TT - 1);                          \
        X = xps[xi_];                                                           \
    }                                                                           \
    float a00, a01, a02, a03, a10, a11, a12, a13;                               \
    ROWDOTH(P, 0 * RSTR, a00, a01, a02, a03)                                    \
    ROWDOTH(P, 1 * RSTR, a10, a11, a12, a13)                                    \
    QRED2(e0_, a00, a10)                                                        \
    QRED2(e1_, a01, a11)                                                        \
    QRED2(e2_, a02, a12)                                                        \
    QRED2(e3_, a03, a13)                                                        \
    if (isL0) {                                                                 \
        if (rk < 2) {                                                           \
            const float iv = rcp1p(__fmaf_rn(xv, wxm0, bgm0) + e0_);            \
            const float fv = rcp1p(__fmaf_rn(xv, wxm1, bgm1) + e1_);            \
            const float gv = __fmaf_rn(2.f, rcp1p(__fmaf_rn(xv, wxm2, bgm2) + e2_), -1.f); \
            const float ov = rcp1p(__fmaf_rn(xv, wxm3, bgm3) + e3_);            \
            cc = __fmaf_rn(fv, cc, iv * gv);                                    \
            const float th = __fmaf_rn(2.f, rcp1p(cc * SGC), -1.f);             \
            *(_Float16*)(wraddr + (L0WOFF)) = (_Float16)(ov * th);              \
        }                                                                       \
    } else {                                                                    \
        /* cross-half (ck vs ck+4) combine: row_ror:12 -> in[(i+4)&15].         \
           ck and ck+4 share rk&1 (same row). Lanes ck>=2 never consume. */     \
        e0_ += dpp_get<0x12C>(e0_);                                             \
        e1_ += dpp_get<0x12C>(e1_);                                             \
        e2_ += dpp_get<0x12C>(e2_);                                             \
        e3_ += dpp_get<0x12C>(e3_);                                             \
        if ((DO_L1) && ck < 2) {                                                \
            const float iv = rcp1p(e0_ + bgm0);                                 \
            const float fv = rcp1p(e1_ + bgm1);                                 \
            const float gv = __fmaf_rn(2.f, rcp1p(e2_ + bgm2), -1.f);           \
            const float ov = rcp1p(e3_ + bgm3);                                 \
            cc = __fmaf_rn(fv, cc, iv * gv);                                    \
            hlast = ov * __fmaf_rn(2.f, rcp1p(cc * SGC), -1.f);                 \
            *(_Float16*)(wraddr + (L1WOFF)) = (_Float16)hlast;                  \
        }                                                                       \
    }                                                                           \
    BARRIER();                                                                  \
}

// Block = 768 threads, **2 batch rows per block, 512 blocks = 2 blocks/CU**.
// Latency-bound regime (R8/R9: halving dots+LDS moved time <8%): two
// co-resident blocks have INDEPENDENT barriers, so one block's waves issue
// while the other drains its barrier-locked serial chain. VGPR-feasible now
// (48 regs with fp16 weights; the R3 failure needed <=85 but sat at 76+).
//   waves 0-3  (tid 0..255):   layer0.  j=tid>>2, ck=tid&3  (16-wide K chunk)
//   waves 4-11 (tid 256..767): layer1.  p=tid-256, j=p>>3, ck=p&7 (K=128=[h1|h2])
// Pipeline: iter i does layer0 step i and layer1 step i-1; ONE barrier per iter.
__global__ __launch_bounds__(768, 6)
void lstm2_kernel(const float* __restrict__ x,
                  const float* __restrict__ Wih0,
                  const float* __restrict__ Whh0,
                  const float* __restrict__ bih0,
                  const float* __restrict__ bhh0,
                  const float* __restrict__ Wih1,
                  const float* __restrict__ Whh1,
                  const float* __restrict__ bih1,
                  const float* __restrict__ bhh1,
                  const float* __restrict__ fcW,
                  const float* __restrict__ fcb,
                  float* __restrict__ out)
{
    __shared__ __align__(16) float arena_f[452];
    char* const arena = (char*)arena_f;

    const int tid  = threadIdx.x;
    const int row0 = blockIdx.x * 2;

    const bool isL0 = (tid < 256);
    const int  p    = isL0 ? tid : (tid - 256);
    const int  j    = isL0 ? (p >> 2) : (p >> 3);
    const int  ck   = isL0 ? (p & 3)  : (p & 7);
    const int  ckk  = (ck < 4) ? ck : (ck - 4);
    const int  rk   = ck & 3;                      // quad lane id
    const bool rr1  = (rk & 1) != 0;               // this lane's row (0/1)

    // ---- weights: 32 packed v2h registers (fp16), gate-prescaled at pack ----
    const float* Wsrc;
    if (isL0)        Wsrc = Whh0;
    else if (ck < 4) Wsrc = Wih1;
    else             Wsrc = Whh1;
    const int kbase = 16 * ckk;
    const float* Wg0 = Wsrc + (0 * HD + j) * HD + kbase;
    const float* Wg1 = Wsrc + (1 * HD + j) * HD + kbase;
    const float* Wg2 = Wsrc + (2 * HD + j) * HD + kbase;
    const float* Wg3 = Wsrc + (3 * HD + j) * HD + kbase;
    const v2h wA0 = packw(Wg0[0],  Wg0[1],  SIC), wA1 = packw(Wg0[2],  Wg0[3],  SIC),
              wA2 = packw(Wg0[4],  Wg0[5],  SIC), wA3 = packw(Wg0[6],  Wg0[7],  SIC),
              wA4 = packw(Wg0[8],  Wg0[9],  SIC), wA5 = packw(Wg0[10], Wg0[11], SIC),
              wA6 = packw(Wg0[12], Wg0[13], SIC), wA7 = packw(Wg0[14], Wg0[15], SIC);
    const v2h wB0 = packw(Wg1[0],  Wg1[1],  SIC), wB1 = packw(Wg1[2],  Wg1[3],  SIC),
              wB2 = packw(Wg1[4],  Wg1[5],  SIC), wB3 = packw(Wg1[6],  Wg1[7],  SIC),
              wB4 = packw(Wg1[8],  Wg1[9],  SIC), wB5 = packw(Wg1[10], Wg1[11], SIC),
              wB6 = packw(Wg1[12], Wg1[13], SIC), wB7 = packw(Wg1[14], Wg1[15], SIC);
    const v2h wC0 = packw(Wg2[0],  Wg2[1],  SGC), wC1 = packw(Wg2[2],  Wg2[3],  SGC),
              wC2 = packw(Wg2[4],  Wg2[5],  SGC), wC3 = packw(Wg2[6],  Wg2[7],  SGC),
              wC4 = packw(Wg2[8],  Wg2[9],  SGC), wC5 = packw(Wg2[10], Wg2[11], SGC),
              wC6 = packw(Wg2[12], Wg2[13], SGC), wC7 = packw(Wg2[14], Wg2[15], SGC);
    const v2h wD0 = packw(Wg3[0],  Wg3[1],  SIC), wD1 = packw(Wg3[2],  Wg3[3],  SIC),
              wD2 = packw(Wg3[4],  Wg3[5],  SIC), wD3 = packw(Wg3[6],  Wg3[7],  SIC),
              wD4 = packw(Wg3[8],  Wg3[9],  SIC), wD5 = packw(Wg3[10], Wg3[11], SIC),
              wD6 = packw(Wg3[12], Wg3[13], SIC), wD7 = packw(Wg3[14], Wg3[15], SIC);

    // Biases / x-weights, f32, pre-scaled, UNMASKED (added once, post-QRED).
    float bgm0, bgm1, bgm2, bgm3, wxm0 = 0.f, wxm1 = 0.f, wxm2 = 0.f, wxm3 = 0.f;
    if (isL0) {
        bgm0 = (bih0[0*HD+j] + bhh0[0*HD+j]) * SIC;
        bgm1 = (bih0[1*HD+j] + bhh0[1*HD+j]) * SIC;
        bgm2 = (bih0[2*HD+j] + bhh0[2*HD+j]) * SGC;
        bgm3 = (bih0[3*HD+j] + bhh0[3*HD+j]) * SIC;
        wxm0 = Wih0[0*HD+j] * SIC;
        wxm1 = Wih0[1*HD+j] * SIC;
        wxm2 = Wih0[2*HD+j] * SGC;
        wxm3 = Wih0[3*HD+j] * SIC;
    } else {
        bgm0 = (bih1[0*HD+j] + bhh1[0*HD+j]) * SIC;
        bgm1 = (bih1[1*HD+j] + bhh1[1*HD+j]) * SIC;
        bgm2 = (bih1[2*HD+j] + bhh1[2*HD+j]) * SGC;
        bgm3 = (bih1[3*HD+j] + bhh1[3*HD+j]) * SIC;
    }

    // LDS read pointers: parity baked into TWO sets; each row read is 2
    // ds_read_b128 at reg+imm (row offsets 0/160).
    const int rdBase = (ck < 4) ? H1_BASE : H2_BASE;   // isL0 has ck<4
    const int rdPh   = (ck < 4) ? 1 : 0;               // h1 readers: (i+1)&1; h2: i&1
    const int coff   = ckk * 32;

    const char* pe0 = arena + rdBase + rdPh * PSTR + coff;
    const char* pe1 = pe0 + 16;
    const char* po0 = arena + rdBase + (rdPh ^ 1) * PSTR + coff;
    const char* po1 = po0 + 16;

    // writers: lane's row rk&1, unit j, fp16 element (gated rk<2 / ck<2)
    char* const wraddr = arena + (isL0 ? H1_BASE : H2_BASE) + (rk & 1) * RSTR + (j << 1);

    // zero h1+h2 (both parities; [0, 1296) covers all h storage)
    for (int z = tid; z < 324; z += 768)
        *(float*)(arena + 4 * z) = 0.f;

    // Each L0 lane streams only ITS row's x (lane row rk&1 -> batch row).
    const float* xps = x + (row0 + (rk & 1)) * TT;
    float xa = 0.f, xb = 0.f;
    if (isL0) { xa = xps[0]; xb = xps[1]; }

    const float fcwj = fcW[j];
    float cc = 0.f, hlast = 0.f;

    __syncthreads();

    STEP(pe, xa, 0, PSTR, false, 2)      // i = 0: L0 only
    STEP(po, xb, PSTR, 0, true, 3)       // i = 1: first L1 step (step 0)
#pragma unroll 1
    for (int i = 2; i < TT; i += 2) {
        STEP(pe, xa, 0, PSTR, true, i + 2)
        STEP(po, xb, PSTR, 0, true, i + 3)
    }
    // tail i = 2048: layer1 step 2047 only (no L0, no h2 store needed)
    if (!isL0) {
        float a00, a01, a02, a03, a10, a11, a12, a13;
        ROWDOTH(pe, 0 * RSTR, a00, a01, a02, a03)
        ROWDOTH(pe, 1 * RSTR, a10, a11, a12, a13)
        QRED2(e0_, a00, a10)
        QRED2(e1_, a01, a11)
        QRED2(e2_, a02, a12)
        QRED2(e3_, a03, a13)
        e0_ += dpp_get<0x12C>(e0_);
        e1_ += dpp_get<0x12C>(e1_);
        e2_ += dpp_get<0x12C>(e2_);
        e3_ += dpp_get<0x12C>(e3_);
        if (ck < 2) {
            const float iv = rcp1p(e0_ + bgm0);
            const float fv = rcp1p(e1_ + bgm1);
            const float gv = __fmaf_rn(2.f, rcp1p(e2_ + bgm2), -1.f);
            const float ov = rcp1p(e3_ + bgm3);
            cc = __fmaf_rn(fv, cc, iv * gv);
            hlast = ov * __fmaf_rn(2.f, rcp1p(cc * SGC), -1.f);
        }
    }
    __syncthreads();

    // ---- FC: out[row] = sum_j h2[T-1][row][j] * fcW[j] + fcb (f32 path) ----
    if (!isL0 && ck < 2)
        *(float*)(arena + FCS_BASE + ((ck * HD + j) << 2)) = hlast * fcwj;
    __syncthreads();

    if (tid < 32) {
        const int r = tid >> 4, seg = tid & 15;
        const float4 v = ((const float4*)(arena + FCS_BASE))[r * 16 + seg];
        float s = (v.x + v.y) + (v.z + v.w);
        s += __shfl_xor(s, 1, 64);
        s += __shfl_xor(s, 2, 64);
        s += __shfl_xor(s, 4, 64);
        s += __shfl_xor(s, 8, 64);
        if (seg == 0) out[row0 + r] = s + fcb[0];
    }
}

extern "C" void kernel_launch(void* const* d_in, const int* in_sizes, int n_in,
                              void* d_out, int out_size, void* d_ws, size_t ws_size,
                              hipStream_t stream) {
    const float* x    = (const float*)d_in[0];
    const float* Wih0 = (const float*)d_in[1];
    const float* Whh0 = (const float*)d_in[2];
    const float* bih0 = (const float*)d_in[3];
    const float* bhh0 = (const float*)d_in[4];
    const float* Wih1 = (const float*)d_in[5];
    const float* Whh1 = (const float*)d_in[6];
    const float* bih1 = (const float*)d_in[7];
    const float* bhh1 = (const float*)d_in[8];
    const float* fcW  = (const float*)d_in[9];
    const float* fcb  = (const float*)d_in[10];
    float* out = (float*)d_out;

    lstm2_kernel<<<512, 768, 0, stream>>>(x, Wih0, Whh0, bih0, bhh0,
                                          Wih1, Whh1, bih1, bhh1,
                                          fcW, fcb, out);
}